// Round 2
// baseline (6933.202 us; speedup 1.0000x reference)
//
#include <hip/hip_runtime.h>

// LSTM encoder-decoder B=512 F=1024 HIST=20 FUT=30 L=3 (fp32 in/out).
// Round 5: 256x256 block tiles (8 waves of 128x64, m201 geometry), split-K z=8.
//   Round-4 diagnosis: 128^2 tiles re-read A x32 / W x4 = 256 MB VMEM per GEMM
//   launch (L2/L3-bound ~25us vs 10us LDS floor, 6.2us MFMA floor). 256^2 tiles
//   halve VMEM (128 MB) and cut LDS/FLOP 24.6->32. Counted-vmcnt(8) pipeline,
//   pre-split bf16 weights, both-sides XOR swizzle all carried over unchanged.

#define BDIM 512
#define FDIM 1024
#define HISTLEN 20
#define LAYERS 3
#define NG 4096
#define KD 1024
#define KSTEPS 8    // 256 k per z-slice / BK=32
#define NZ 8        // split-K partials

typedef __attribute__((ext_vector_type(8))) short short8;   // 8 bf16 = 4 VGPRs
typedef __attribute__((ext_vector_type(4))) float f32x4;    // MFMA accumulator
typedef __attribute__((ext_vector_type(4))) unsigned short u16x4;

__device__ __forceinline__ float sigf(float x) { return 1.f / (1.f + __expf(-x)); }
__device__ __forceinline__ float tanh_fast(float x) {
    float e = __expf(-2.f * fabsf(x));
    float r = (1.f - e) / (1.f + e);
    return copysignf(r, x);
}
__device__ __forceinline__ ushort bfhi(float w) { return (ushort)(__float_as_uint(w) >> 16); }
__device__ __forceinline__ float hif(float w) { return __uint_as_float(__float_as_uint(w) & 0xFFFF0000u); }
__device__ __forceinline__ ushort bflo(float w) { return bfhi(w - hif(w)); }

__device__ __forceinline__ void gl16(const ushort* g, ushort* l) {
    __builtin_amdgcn_global_load_lds(
        (const __attribute__((address_space(1))) unsigned int*)g,
        (__attribute__((address_space(3))) unsigned int*)l, 16, 0, 0);
}

// ---------------- one-time weight pre-split: fp32 W -> bf16 hi/lo --------------
// slot = l*2+s (s=0 Wih, 1 Whh), each slot 2^22 elems.
__global__ void prep_w(const float* __restrict__ Wih, const float* __restrict__ Whh,
                       ushort* __restrict__ Whi, ushort* __restrict__ Wlo)
{
    size_t i4 = ((size_t)blockIdx.x * 256 + threadIdx.x) * 4;
    size_t slot = i4 >> 22;
    size_t off  = i4 & 0x3FFFFFu;
    const float* src = ((slot & 1) ? Whh : Wih) + ((slot >> 1) << 22) + off;
    float4 v = *(const float4*)src;
    u16x4 hi, lo;
    #pragma unroll
    for (int e = 0; e < 4; ++e) {
        float w = ((const float*)&v)[e];
        unsigned u = __float_as_uint(w);
        hi[e] = (ushort)(u >> 16);
        float r = w - __uint_as_float(u & 0xFFFF0000u);
        lo[e] = (ushort)(__float_as_uint(r) >> 16);
    }
    *(u16x4*)(Whi + i4) = hi;
    *(u16x4*)(Wlo + i4) = lo;
}

// ---------------- GEMM: gp[z][512,4096] partial = A(s) @ W(s)^T over K/4 -------
// z = kh*2 + s, kh in 0..3 (K-chunk of 256). Tiles 256x256, BK=32, 512 thr =
// 8 waves of 128x64. 256 blocks = 1/CU, 2 waves/SIMD. LDS 2 x 64 KB dbuf.
// Both-sides XOR swizzle: chunk ^= (row>>1)&3 on global SOURCE and on ds_read.
__global__ __launch_bounds__(512, 2) void gemm_split(
    const ushort* __restrict__ A0hi, const ushort* __restrict__ A0lo,
    const ushort* __restrict__ W0hi, const ushort* __restrict__ W0lo,
    const ushort* __restrict__ A1hi, const ushort* __restrict__ A1lo,
    const ushort* __restrict__ W1hi, const ushort* __restrict__ W1lo,
    float* __restrict__ gp)
{
    // [buf][arrays Ahi|Alo|Whi|Wlo, each 256x32 bf16] = 2 x 64 KB
    __shared__ __attribute__((aligned(16))) ushort lds[2][4 * 8192];

    const int z  = blockIdx.z;
    const int s  = z & 1;
    const int kh = z >> 1;
    const ushort* Ahi = s ? A1hi : A0hi;
    const ushort* Alo = s ? A1lo : A0lo;
    const ushort* Whi = s ? W1hi : W0hi;
    const ushort* Wlo = s ? W1lo : W0lo;
    float* out = gp + (size_t)z * BDIM * NG;

    const int tid = threadIdx.x;
    const int m0 = blockIdx.y * 256;
    const int n0 = blockIdx.x * 256;

    // staging: thread -> (row = tid>>2 in 0..127, chunk = tid&3); pass 1 adds 128
    // rows. Source chunk pre-swizzled: chunk' = chunk ^ ((row>>1)&3). Row stride
    // of the LDS tile is 32 bf16 = 64 B; dest = base + tid*16B (wave-linear).
    const int srow = tid >> 2;
    const int scol = ((tid & 3) ^ ((srow >> 1) & 3)) << 3;   // bf16 elems
    const int kbeg = kh * 256;

    const ushort* pAhi = Ahi + (size_t)(m0 + srow) * KD + kbeg + scol;
    const ushort* pAlo = Alo + (size_t)(m0 + srow) * KD + kbeg + scol;
    const ushort* pWhi = Whi + (size_t)(n0 + srow) * KD + kbeg + scol;
    const ushort* pWlo = Wlo + (size_t)(n0 + srow) * KD + kbeg + scol;
    const int rstep = 128 * KD;

    const int lane = tid & 63;
    const int wid  = tid >> 6;
    const int wm = (wid >> 2) * 128;   // 2 wave-rows
    const int wn = (wid & 3) * 64;     // 4 wave-cols
    const int frow = lane & 15;
    const int oct  = lane >> 4;

    int a_e[8], w_e[4];   // ushort-elem offsets within a tile array (swizzled)
    #pragma unroll
    for (int i = 0; i < 8; ++i) {
        int ra = wm + i * 16 + frow;
        a_e[i] = ra * 32 + (((oct ^ (ra >> 1)) & 3) << 3);
    }
    #pragma unroll
    for (int j = 0; j < 4; ++j) {
        int rw = wn + j * 16 + frow;
        w_e[j] = rw * 32 + (((oct ^ (rw >> 1)) & 3) << 3);
    }

    f32x4 acc[8][4] = {};

    auto STAGE = [&](ushort* buf, int kk) {   // 8 x global_load_lds (16B each)
        ushort* d0 = buf + tid * 8;           // rows 0..127 of each array
        gl16(pAhi + kk,         d0);
        gl16(pAlo + kk,         d0 + 8192);
        gl16(pWhi + kk,         d0 + 16384);
        gl16(pWlo + kk,         d0 + 24576);
        ushort* d1 = d0 + 4096;               // rows 128..255
        gl16(pAhi + rstep + kk, d1);
        gl16(pAlo + rstep + kk, d1 + 8192);
        gl16(pWhi + rstep + kk, d1 + 16384);
        gl16(pWlo + rstep + kk, d1 + 24576);
    };

    auto COMPUTE = [&](const ushort* buf) {
        short8 fah[8], fal[8];
        #pragma unroll
        for (int i = 0; i < 8; ++i) {
            fah[i] = *(const short8*)(buf + a_e[i]);
            fal[i] = *(const short8*)(buf + 8192 + a_e[i]);
        }
        __builtin_amdgcn_s_setprio(1);
        #pragma unroll
        for (int j = 0; j < 4; ++j) {
            short8 fbh = *(const short8*)(buf + 16384 + w_e[j]);
            short8 fbl = *(const short8*)(buf + 24576 + w_e[j]);
            #pragma unroll
            for (int i = 0; i < 8; ++i) {
                acc[i][j] = __builtin_amdgcn_mfma_f32_16x16x32_bf16(fah[i], fbh, acc[i][j], 0, 0, 0);
                acc[i][j] = __builtin_amdgcn_mfma_f32_16x16x32_bf16(fal[i], fbh, acc[i][j], 0, 0, 0);
                acc[i][j] = __builtin_amdgcn_mfma_f32_16x16x32_bf16(fah[i], fbl, acc[i][j], 0, 0, 0);
            }
        }
        __builtin_amdgcn_s_setprio(0);
        // all ds_reads were consumed by MFMAs (compiler lgkmcnt) -> buffer free
        __builtin_amdgcn_s_barrier();
    };

    STAGE(&lds[0][0], 0);                     // prologue: tile 0 in flight (8)
    #pragma unroll 1
    for (int t = 0; t < KSTEPS - 1; ++t) {
        // issue t+1 (safe: end-of-COMPUTE barrier of t-1 freed this buffer)
        STAGE(&lds[(t + 1) & 1][0], (t + 1) * 32);
        asm volatile("s_waitcnt vmcnt(8)" ::: "memory");   // tile-t loads landed
        __builtin_amdgcn_sched_barrier(0);
        __builtin_amdgcn_s_barrier();         // everyone's tile-t landed
        __builtin_amdgcn_sched_barrier(0);
        COMPUTE(&lds[t & 1][0]);
    }
    asm volatile("s_waitcnt vmcnt(0)" ::: "memory");
    __builtin_amdgcn_s_barrier();
    COMPUTE(&lds[(KSTEPS - 1) & 1][0]);

    // C/D layout: row=(lane>>4)*4+reg, col=lane&15 (verified m89/m91)
    #pragma unroll
    for (int i = 0; i < 8; ++i) {
        #pragma unroll
        for (int j = 0; j < 4; ++j) {
            int col = n0 + wn + j * 16 + frow;
            #pragma unroll
            for (int r = 0; r < 4; ++r) {
                int row = m0 + wm + i * 16 + oct * 4 + r;
                out[(size_t)row * NG + col] = acc[i][j][r];
            }
        }
    }
}

// ---------------- elementwise cell update (sum 8 partials + biases) ------------
__global__ void cell_fuse(const float* __restrict__ gp,
                          const float* __restrict__ bi, const float* __restrict__ bh,
                          float* __restrict__ c,
                          ushort* __restrict__ Hhi, ushort* __restrict__ Hlo,
                          float* __restrict__ y, int t, int fut)
{
    const size_t MN = (size_t)BDIM * NG;
    int idx = blockIdx.x * blockDim.x + threadIdx.x;   // < B*F
    int b = idx >> 10, f = idx & 1023;
    float g4[4];
    #pragma unroll
    for (int g = 0; g < 4; ++g) g4[g] = bi[g * FDIM + f] + bh[g * FDIM + f];
    const float* gz = gp + (size_t)b * NG;
    #pragma unroll
    for (int zz = 0; zz < NZ; ++zz) {
        #pragma unroll
        for (int g = 0; g < 4; ++g) g4[g] += gz[g * FDIM + f];
        gz += MN;
    }
    float cn = sigf(g4[1]) * c[idx] + sigf(g4[0]) * tanh_fast(g4[2]);
    float hn = sigf(g4[3]) * tanh_fast(cn);
    c[idx] = cn;
    Hhi[idx] = bfhi(hn);
    Hlo[idx] = bflo(hn);
    if (y) y[(size_t)idx * fut + t] = hn;
}

// x_t from seq [B,F,HIST] -> split bf16
__global__ void pack_split(const float* __restrict__ seq,
                           ushort* __restrict__ Xhi, ushort* __restrict__ Xlo, int t)
{
    int idx = blockIdx.x * blockDim.x + threadIdx.x;
    float v = seq[(size_t)idx * HISTLEN + t];
    Xhi[idx] = bfhi(v);
    Xlo[idx] = bflo(v);
}

// fp32 vector -> split bf16 (decoder t=0 input = c[2])
__global__ void split_vec(const float* __restrict__ src,
                          ushort* __restrict__ hi, ushort* __restrict__ lo)
{
    int idx = blockIdx.x * blockDim.x + threadIdx.x;
    float v = src[idx];
    hi[idx] = bfhi(v);
    lo[idx] = bflo(v);
}

extern "C" void kernel_launch(void* const* d_in, const int* in_sizes, int n_in,
                              void* d_out, int out_size, void* d_ws, size_t ws_size,
                              hipStream_t stream)
{
    const float* seq = (const float*)d_in[0];
    const float* Wih = (const float*)d_in[1];
    const float* Whh = (const float*)d_in[2];
    const float* bih = (const float*)d_in[3];
    const float* bhh = (const float*)d_in[4];
    float* out = (float*)d_out;

    const int fut = out_size / (BDIM * FDIM);           // 30
    const size_t BF = (size_t)BDIM * FDIM;
    const size_t MN = (size_t)BDIM * NG;
    const size_t Wsl = (size_t)1 << 22;                 // elems per (l,s) weight slot

    // ws: c[3BF]f32 | Hhi[3BF]u16 | Hlo | Xhi[BF]u16 | Xlo | gp[NZ*MN]f32 |
    //     Whi[6*Wsl]u16 | Wlo[6*Wsl]u16   (total ~183 MiB)
    float*  c   = (float*)d_ws;
    ushort* Hhi = (ushort*)(c + LAYERS * BF);
    ushort* Hlo = Hhi + LAYERS * BF;
    ushort* Xhi = Hlo + LAYERS * BF;
    ushort* Xlo = Xhi + BF;
    float*  gp  = (float*)(Xlo + BF);
    ushort* Whi = (ushort*)(gp + NZ * MN);
    ushort* Wlo = Whi + 6 * Wsl;

    const size_t need = (size_t)((char*)(Wlo + 6 * Wsl) - (char*)d_ws);
    if (ws_size < need) return;                         // clean fail, no OOB

    hipMemsetAsync(d_ws, 0, LAYERS * BF * 8, stream);   // zero c, Hhi, Hlo
    prep_w<<<24576, 256, 0, stream>>>(Wih, Whh, Whi, Wlo);

    dim3 ggrid(NG / 256, BDIM / 256, NZ);               // (16, 2, 8) = 256 WGs
    const int cgrid = (int)(BF / 256);

    for (int t = 0; t < HISTLEN + fut; ++t) {
        const bool dec = (t >= HISTLEN);
        if (!dec) {
            pack_split<<<cgrid, 256, 0, stream>>>(seq, Xhi, Xlo, t);
        } else if (t == HISTLEN) {
            split_vec<<<cgrid, 256, 0, stream>>>(c + 2 * BF, Xhi, Xlo);
        }
        for (int l = 0; l < LAYERS; ++l) {
            const ushort* axh;
            const ushort* axl;
            if (l > 0)        { axh = Hhi + (size_t)(l - 1) * BF; axl = Hlo + (size_t)(l - 1) * BF; }
            else if (!dec || t == HISTLEN) { axh = Xhi; axl = Xlo; }
            else              { axh = Hhi + 2 * BF; axl = Hlo + 2 * BF; }

            gemm_split<<<ggrid, 512, 0, stream>>>(
                axh, axl, Whi + (size_t)(2 * l) * Wsl, Wlo + (size_t)(2 * l) * Wsl,
                Hhi + (size_t)l * BF, Hlo + (size_t)l * BF,
                Whi + (size_t)(2 * l + 1) * Wsl, Wlo + (size_t)(2 * l + 1) * Wsl,
                gp);

            cell_fuse<<<cgrid, 256, 0, stream>>>(
                gp, bih + l * NG, bhh + l * NG,
                c + (size_t)l * BF, Hhi + (size_t)l * BF, Hlo + (size_t)l * BF,
                (dec && l == LAYERS - 1) ? out : nullptr, dec ? t - HISTLEN : 0, fut);
        }
    }
}

// Round 3
// 5797.836 us; speedup vs baseline: 1.1958x; 1.1958x over previous
//
#include <hip/hip_runtime.h>

// LSTM encoder-decoder B=512 F=1024 HIST=20 FUT=30 L=3 (fp32 in/out).
// Round 6: round-4 structure (128^2 tiles, z=4, 2 blocks/CU, counted-vmcnt
//   pipeline, pre-split bf16 weights) + XCD-aware block remap.
//   Round-5 post-mortem: 256^2 tiles (1 block/CU, z=8) regressed 5826->6933;
//   cross-block latency hiding + cheap cell_fuse beat lower VMEM traffic.
//   Round-6 theory: default lb%8 XCD map gives each XCD ~8MB working set
//   (> 4MiB L2) -> 256MB/launch of re-reads served by L3 (~17-26us floor).
//   Remap: XCD k owns z=k>>1, x in [(k&1)*16, +16), all y -> WS ~5MB, k-swept
//   in lockstep by 64 co-resident blocks -> re-reads become L2 hits.

#define BDIM 512
#define FDIM 1024
#define HISTLEN 20
#define LAYERS 3
#define NG 4096
#define KD 1024
#define KSTEPS 16   // 512 k per block-chunk / BK=32

typedef __attribute__((ext_vector_type(8))) short short8;   // 8 bf16 = 4 VGPRs
typedef __attribute__((ext_vector_type(4))) float f32x4;    // MFMA accumulator
typedef __attribute__((ext_vector_type(4))) unsigned short u16x4;

__device__ __forceinline__ float sigf(float x) { return 1.f / (1.f + __expf(-x)); }
__device__ __forceinline__ float tanh_fast(float x) {
    float e = __expf(-2.f * fabsf(x));
    float r = (1.f - e) / (1.f + e);
    return copysignf(r, x);
}
__device__ __forceinline__ ushort bfhi(float w) { return (ushort)(__float_as_uint(w) >> 16); }
__device__ __forceinline__ float hif(float w) { return __uint_as_float(__float_as_uint(w) & 0xFFFF0000u); }
__device__ __forceinline__ ushort bflo(float w) { return bfhi(w - hif(w)); }

__device__ __forceinline__ void gl16(const ushort* g, ushort* l) {
    __builtin_amdgcn_global_load_lds(
        (const __attribute__((address_space(1))) unsigned int*)g,
        (__attribute__((address_space(3))) unsigned int*)l, 16, 0, 0);
}

// ---------------- one-time weight pre-split: fp32 W -> bf16 hi/lo --------------
// slot = l*2+s (s=0 Wih, 1 Whh), each slot 2^22 elems.
__global__ void prep_w(const float* __restrict__ Wih, const float* __restrict__ Whh,
                       ushort* __restrict__ Whi, ushort* __restrict__ Wlo)
{
    size_t i4 = ((size_t)blockIdx.x * 256 + threadIdx.x) * 4;
    size_t slot = i4 >> 22;
    size_t off  = i4 & 0x3FFFFFu;
    const float* src = ((slot & 1) ? Whh : Wih) + ((slot >> 1) << 22) + off;
    float4 v = *(const float4*)src;
    u16x4 hi, lo;
    #pragma unroll
    for (int e = 0; e < 4; ++e) {
        float w = ((const float*)&v)[e];
        unsigned u = __float_as_uint(w);
        hi[e] = (ushort)(u >> 16);
        float r = w - __uint_as_float(u & 0xFFFF0000u);
        lo[e] = (ushort)(__float_as_uint(r) >> 16);
    }
    *(u16x4*)(Whi + i4) = hi;
    *(u16x4*)(Wlo + i4) = lo;
}

// ---------------- GEMM: gp[z][512,4096] partial = A(s) @ W(s)^T over k-half ----
// z = kh*2 + s. All operands pre-split bf16. Tiles 128x128, BK=32, 256 thr,
// 512 blocks = 2/CU. LDS linear [128][32] per tile, XOR-swizzle chunk^=(row>>1)&3
// applied on global SOURCE addr (stage) and on ds_read addr (both-sides, m173).
// Block remap: lb -> (xcd = lb&7, j = lb>>3); z = xcd>>1, x = (xcd&1)*16+(j&15),
// y = j>>4. Bijective; each XCD owns one z-slice and a 16-wide x-band.
__global__ __launch_bounds__(256, 2) void gemm_split(
    const ushort* __restrict__ A0hi, const ushort* __restrict__ A0lo,
    const ushort* __restrict__ W0hi, const ushort* __restrict__ W0lo,
    const ushort* __restrict__ A1hi, const ushort* __restrict__ A1lo,
    const ushort* __restrict__ W1hi, const ushort* __restrict__ W1lo,
    float* __restrict__ gp)
{
    // [buf][tile: Ahi,Alo,Whi,Wlo][128*32 bf16] = 64 KB total
    __shared__ __attribute__((aligned(16))) ushort lds[2][4][4096];

    const int lb  = blockIdx.x + 32 * blockIdx.y + 128 * blockIdx.z;  // 0..511
    const int xcd = lb & 7;
    const int jj  = lb >> 3;                  // 0..63 (slot within XCD)
    const int z   = xcd >> 1;                 // 2 XCDs per z-slice
    const int bx  = (xcd & 1) * 16 + (jj & 15);
    const int by  = jj >> 4;

    const int s  = z & 1;
    const int kh = z >> 1;
    const ushort* Ahi = s ? A1hi : A0hi;
    const ushort* Alo = s ? A1lo : A0lo;
    const ushort* Whi = s ? W1hi : W0hi;
    const ushort* Wlo = s ? W1lo : W0lo;
    float* out = gp + (size_t)z * BDIM * NG;

    const int tid = threadIdx.x;
    const int m0 = by * 128;
    const int n0 = bx * 128;

    // staging: thread -> (row=tid>>2, chunk=tid&3), pass 1 adds 64 rows.
    // source chunk pre-swizzled: chunk' = chunk ^ ((row>>1)&3)
    const int srow = tid >> 2;
    const int scol = ((tid & 3) ^ ((srow >> 1) & 3)) << 3;   // bf16 elems
    const int kbeg = kh * (KD / 2);

    const ushort* pAhi = Ahi + (size_t)(m0 + srow) * KD + kbeg + scol;
    const ushort* pAlo = Alo + (size_t)(m0 + srow) * KD + kbeg + scol;
    const ushort* pWhi = Whi + (size_t)(n0 + srow) * KD + kbeg + scol;
    const ushort* pWlo = Wlo + (size_t)(n0 + srow) * KD + kbeg + scol;
    const int rstep = 64 * KD;

    const int lane = tid & 63;
    const int wid  = tid >> 6;
    const int wm = (wid & 1) * 64;
    const int wn = (wid >> 1) * 64;
    const int frow = lane & 15;
    const int oct  = lane >> 4;

    int a_e[4], w_e[4];   // ushort-elem offsets within a tile (swizzled read)
    #pragma unroll
    for (int i = 0; i < 4; ++i) {
        int ra = wm + i * 16 + frow;
        a_e[i] = ra * 32 + (((oct ^ (ra >> 1)) & 3) << 3);
        int rw = wn + i * 16 + frow;
        w_e[i] = rw * 32 + (((oct ^ (rw >> 1)) & 3) << 3);
    }

    f32x4 acc[4][4] = {};

    auto STAGE = [&](ushort* buf, int kk) {   // 8 x global_load_lds (16B each)
        ushort* d0 = buf + tid * 8;           // chunks 0..255
        gl16(pAhi + kk,         d0);
        gl16(pAlo + kk,         d0 + 4096);
        gl16(pWhi + kk,         d0 + 8192);
        gl16(pWlo + kk,         d0 + 12288);
        ushort* d1 = d0 + 2048;               // chunks 256..511 (rows +64)
        gl16(pAhi + rstep + kk, d1);
        gl16(pAlo + rstep + kk, d1 + 4096);
        gl16(pWhi + rstep + kk, d1 + 8192);
        gl16(pWlo + rstep + kk, d1 + 12288);
    };

    auto COMPUTE = [&](const ushort* buf) {
        short8 fah[4], fal[4], fbh[4], fbl[4];
        #pragma unroll
        for (int i = 0; i < 4; ++i) {
            fah[i] = *(const short8*)(buf + a_e[i]);
            fal[i] = *(const short8*)(buf + 4096 + a_e[i]);
            fbh[i] = *(const short8*)(buf + 8192 + w_e[i]);
            fbl[i] = *(const short8*)(buf + 12288 + w_e[i]);
        }
        asm volatile("s_waitcnt lgkmcnt(0)" ::: "memory");
        __builtin_amdgcn_sched_barrier(0);
        __builtin_amdgcn_s_barrier();         // barrier B: all reads of buf done
        __builtin_amdgcn_sched_barrier(0);
        __builtin_amdgcn_s_setprio(1);
        #pragma unroll
        for (int j = 0; j < 4; ++j) {
            #pragma unroll
            for (int i = 0; i < 4; ++i) {
                acc[i][j] = __builtin_amdgcn_mfma_f32_16x16x32_bf16(fah[i], fbh[j], acc[i][j], 0, 0, 0);
                acc[i][j] = __builtin_amdgcn_mfma_f32_16x16x32_bf16(fal[i], fbh[j], acc[i][j], 0, 0, 0);
                acc[i][j] = __builtin_amdgcn_mfma_f32_16x16x32_bf16(fah[i], fbl[j], acc[i][j], 0, 0, 0);
            }
        }
        __builtin_amdgcn_s_setprio(0);
    };

    STAGE(&lds[0][0][0], 0);                  // prologue: tile 0 in flight (8)
    #pragma unroll 1
    for (int t = 0; t < KSTEPS - 1; ++t) {
        // issue t+1 (safe: barrier B of t-1 proved all reads of this buf done)
        STAGE(&lds[(t + 1) & 1][0][0], (t + 1) * 32);
        asm volatile("s_waitcnt vmcnt(8)" ::: "memory");   // my tile-t loads landed
        __builtin_amdgcn_sched_barrier(0);
        __builtin_amdgcn_s_barrier();         // barrier A: everyone's tile-t landed
        __builtin_amdgcn_sched_barrier(0);
        COMPUTE(&lds[t & 1][0][0]);
    }
    asm volatile("s_waitcnt vmcnt(0)" ::: "memory");
    __builtin_amdgcn_s_barrier();
    COMPUTE(&lds[(KSTEPS - 1) & 1][0][0]);

    // C/D layout: row=(lane>>4)*4+reg, col=lane&15 (verified m89/m91)
    #pragma unroll
    for (int i = 0; i < 4; ++i) {
        #pragma unroll
        for (int j = 0; j < 4; ++j) {
            int col = n0 + wn + j * 16 + frow;
            #pragma unroll
            for (int r = 0; r < 4; ++r) {
                int row = m0 + wm + i * 16 + oct * 4 + r;
                out[(size_t)row * NG + col] = acc[i][j][r];
            }
        }
    }
}

// ---------------- elementwise cell update (sum 4 partials + biases) ------------
__global__ void cell_fuse(const float* __restrict__ gp,
                          const float* __restrict__ bi, const float* __restrict__ bh,
                          float* __restrict__ c,
                          ushort* __restrict__ Hhi, ushort* __restrict__ Hlo,
                          float* __restrict__ y, int t, int fut)
{
    const size_t MN = (size_t)BDIM * NG;
    int idx = blockIdx.x * blockDim.x + threadIdx.x;   // < B*F
    int b = idx >> 10, f = idx & 1023;
    const float* g0 = gp + (size_t)b * NG;
    const float* g1 = g0 + MN;
    const float* g2 = g1 + MN;
    const float* g3 = g2 + MN;
    float ig = g0[f] + g1[f] + g2[f] + g3[f] + bi[f] + bh[f];
    float fg = g0[FDIM + f] + g1[FDIM + f] + g2[FDIM + f] + g3[FDIM + f]
             + bi[FDIM + f] + bh[FDIM + f];
    float gg = g0[2 * FDIM + f] + g1[2 * FDIM + f] + g2[2 * FDIM + f] + g3[2 * FDIM + f]
             + bi[2 * FDIM + f] + bh[2 * FDIM + f];
    float og = g0[3 * FDIM + f] + g1[3 * FDIM + f] + g2[3 * FDIM + f] + g3[3 * FDIM + f]
             + bi[3 * FDIM + f] + bh[3 * FDIM + f];
    float cn = sigf(fg) * c[idx] + sigf(ig) * tanh_fast(gg);
    float hn = sigf(og) * tanh_fast(cn);
    c[idx] = cn;
    Hhi[idx] = bfhi(hn);
    Hlo[idx] = bflo(hn);
    if (y) y[(size_t)idx * fut + t] = hn;
}

// x_t from seq [B,F,HIST] -> split bf16
__global__ void pack_split(const float* __restrict__ seq,
                           ushort* __restrict__ Xhi, ushort* __restrict__ Xlo, int t)
{
    int idx = blockIdx.x * blockDim.x + threadIdx.x;
    float v = seq[(size_t)idx * HISTLEN + t];
    Xhi[idx] = bfhi(v);
    Xlo[idx] = bflo(v);
}

// fp32 vector -> split bf16 (decoder t=0 input = c[2])
__global__ void split_vec(const float* __restrict__ src,
                          ushort* __restrict__ hi, ushort* __restrict__ lo)
{
    int idx = blockIdx.x * blockDim.x + threadIdx.x;
    float v = src[idx];
    hi[idx] = bfhi(v);
    lo[idx] = bflo(v);
}

extern "C" void kernel_launch(void* const* d_in, const int* in_sizes, int n_in,
                              void* d_out, int out_size, void* d_ws, size_t ws_size,
                              hipStream_t stream)
{
    const float* seq = (const float*)d_in[0];
    const float* Wih = (const float*)d_in[1];
    const float* Whh = (const float*)d_in[2];
    const float* bih = (const float*)d_in[3];
    const float* bhh = (const float*)d_in[4];
    float* out = (float*)d_out;

    const int fut = out_size / (BDIM * FDIM);           // 30
    const size_t BF = (size_t)BDIM * FDIM;
    const size_t MN = (size_t)BDIM * NG;
    const size_t Wsl = (size_t)1 << 22;                 // elems per (l,s) weight slot

    // ws: c[3BF]f32 | Hhi[3BF]u16 | Hlo | Xhi[BF]u16 | Xlo | gp[4*MN]f32 |
    //     Whi[6*Wsl]u16 | Wlo[6*Wsl]u16   (total ~149 MiB)
    float*  c   = (float*)d_ws;
    ushort* Hhi = (ushort*)(c + LAYERS * BF);
    ushort* Hlo = Hhi + LAYERS * BF;
    ushort* Xhi = Hlo + LAYERS * BF;
    ushort* Xlo = Xhi + BF;
    float*  gp  = (float*)(Xlo + BF);
    ushort* Whi = (ushort*)(gp + 4 * MN);
    ushort* Wlo = Whi + 6 * Wsl;

    const size_t need = (size_t)((char*)(Wlo + 6 * Wsl) - (char*)d_ws);
    if (ws_size < need) return;                         // clean fail, no OOB

    hipMemsetAsync(d_ws, 0, LAYERS * BF * 8, stream);   // zero c, Hhi, Hlo
    prep_w<<<24576, 256, 0, stream>>>(Wih, Whh, Whi, Wlo);

    dim3 ggrid(NG / 128, BDIM / 128, 4);                // (32, 4, 4) = 512 WGs
    const int cgrid = (int)(BF / 256);

    for (int t = 0; t < HISTLEN + fut; ++t) {
        const bool dec = (t >= HISTLEN);
        if (!dec) {
            pack_split<<<cgrid, 256, 0, stream>>>(seq, Xhi, Xlo, t);
        } else if (t == HISTLEN) {
            split_vec<<<cgrid, 256, 0, stream>>>(c + 2 * BF, Xhi, Xlo);
        }
        for (int l = 0; l < LAYERS; ++l) {
            const ushort* axh;
            const ushort* axl;
            if (l > 0)        { axh = Hhi + (size_t)(l - 1) * BF; axl = Hlo + (size_t)(l - 1) * BF; }
            else if (!dec || t == HISTLEN) { axh = Xhi; axl = Xlo; }
            else              { axh = Hhi + 2 * BF; axl = Hlo + 2 * BF; }

            gemm_split<<<ggrid, 256, 0, stream>>>(
                axh, axl, Whi + (size_t)(2 * l) * Wsl, Wlo + (size_t)(2 * l) * Wsl,
                Hhi + (size_t)l * BF, Hlo + (size_t)l * BF,
                Whi + (size_t)(2 * l + 1) * Wsl, Wlo + (size_t)(2 * l + 1) * Wsl,
                gp);

            cell_fuse<<<cgrid, 256, 0, stream>>>(
                gp, bih + l * NG, bhh + l * NG,
                c + (size_t)l * BF, Hhi + (size_t)l * BF, Hlo + (size_t)l * BF,
                (dec && l == LAYERS - 1) ? out : nullptr, dec ? t - HISTLEN : 0, fut);
        }
    }
}